// Round 2
// baseline (60.444 us; speedup 1.0000x reference)
//
#include <hip/hip_runtime.h>

typedef int int4v __attribute__((ext_vector_type(4)));

// Problem constants
#define BATCH   64
#define HH      56
#define WW      56
#define IN_C    64
#define OUT_C   128
#define NPIX    200704      // 64*56*56
#define KTOT    576         // 3*3*64
#define N_W     73728       // 128*3*3*64
#define N_OUT   25690112    // NPIX * OUT_C

// Conv tiling
#define BLOCK_PIX 64
#define ROWB      592       // 576 + 16 pad: LDS row stride (bank-safe)

// ---------------------------------------------------------------------------
// Pack weights into B-fragment order for mfma_i32_16x16x64_i8:
//   dest byte t = ((kt*8 + nt)*64 + lane)*16 + byte
//   holds W[k][n] with k = kt*64 + (lane>>4)*16 + byte, n = nt*16 + (lane&15)
// Source OHWI flat index = n*576 + k  (since k = (kh*3+kw)*64+ic).
__global__ __launch_bounds__(256) void pack_w_kernel(const int* __restrict__ wgt,
                                                     char* __restrict__ w8) {
    int t = blockIdx.x * 256 + threadIdx.x;   // t < N_W == 73728 exactly
    int byte = t & 15;
    int lane = (t >> 4) & 63;
    int ntk  = t >> 10;
    int nt   = ntk & 7;
    int kt   = ntk >> 3;                      // kt < 9
    int k = kt * 64 + ((lane >> 4) << 4) + byte;
    int n = nt * 16 + (lane & 15);
    w8[t] = (char)wgt[n * KTOT + k];
}

// ---------------------------------------------------------------------------
// Fused MFMA implicit-GEMM conv: reads x as int32 NHWC, packs to int8 in
// registers, stages the 64x576 A-tile in LDS, 4 waves x (4 M x 2 N x 9 K)
// MFMAs per block. Wave wv owns channels [wv*32, wv*32+32).
__global__ __launch_bounds__(256) void conv_fused_kernel(const int* __restrict__ x32,
                                                         const char* __restrict__ w8,
                                                         const int* __restrict__ bias,
                                                         int* __restrict__ out) {
    __shared__ char lds[BLOCK_PIX * ROWB];

    const int tid   = threadIdx.x;
    const int lane  = tid & 63;
    const int wv    = tid >> 6;
    const int l15   = lane & 15;
    const int l4    = lane >> 4;
    const int mbase = blockIdx.x * BLOCK_PIX;

    // B fragments for this wave, held in registers for the whole block.
    int4v b[9][2];
#pragma unroll
    for (int kt = 0; kt < 9; ++kt) {
#pragma unroll
        for (int ntl = 0; ntl < 2; ++ntl) {
            int nt = wv * 2 + ntl;
            b[kt][ntl] = *(const int4v*)(w8 + ((((kt * 8 + nt) * 64) + lane) << 4));
        }
    }

    // Fused stage: 4 threads per pixel; thread covers 16 channels (64 B int32
    // -> 16 B int8) per tap position. 9 positions x 64 pixels.
    const int p = tid >> 2;        // pixel within tile (0..63)
    const int q = tid & 3;         // channel quarter (0..3)
    int pg = mbase + p;
    int n  = pg / 3136;
    int r2 = pg - n * 3136;
    int h  = r2 / 56;
    int w  = r2 - h * 56;
    char* dst_base = lds + p * ROWB + (q << 4);

#pragma unroll
    for (int kh = 0; kh < 3; ++kh) {
        int hx = h + kh - 1;
#pragma unroll
        for (int kw = 0; kw < 3; ++kw) {
            int wx = w + kw - 1;
            int4v pk = {0, 0, 0, 0};
            if ((unsigned)hx < 56u && (unsigned)wx < 56u) {
                const int4v* src =
                    (const int4v*)(x32 + (((n * 56 + hx) * 56 + wx) << 6) + (q << 4));
                int4v a0 = src[0], a1 = src[1], a2 = src[2], a3 = src[3];
                pk.x = (a0.x & 0xff) | ((a0.y & 0xff) << 8) | ((a0.z & 0xff) << 16) | (a0.w << 24);
                pk.y = (a1.x & 0xff) | ((a1.y & 0xff) << 8) | ((a1.z & 0xff) << 16) | (a1.w << 24);
                pk.z = (a2.x & 0xff) | ((a2.y & 0xff) << 8) | ((a2.z & 0xff) << 16) | (a2.w << 24);
                pk.w = (a3.x & 0xff) | ((a3.y & 0xff) << 8) | ((a3.z & 0xff) << 16) | (a3.w << 24);
            }
            *(int4v*)(dst_base + (kh * 3 + kw) * 64) = pk;
        }
    }
    __syncthreads();

    int4v acc[4][2];
#pragma unroll
    for (int mt = 0; mt < 4; ++mt) {
        acc[mt][0] = (int4v){0, 0, 0, 0};
        acc[mt][1] = (int4v){0, 0, 0, 0};
    }

#pragma unroll
    for (int kt = 0; kt < 9; ++kt) {
#pragma unroll
        for (int mt = 0; mt < 4; ++mt) {
            int4v a = *(const int4v*)(lds + (mt * 16 + l15) * ROWB + kt * 64 + (l4 << 4));
            acc[mt][0] = __builtin_amdgcn_mfma_i32_16x16x64_i8(a, b[kt][0], acc[mt][0], 0, 0, 0);
            acc[mt][1] = __builtin_amdgcn_mfma_i32_16x16x64_i8(a, b[kt][1], acc[mt][1], 0, 0, 0);
        }
    }

    // Epilogue: D col = lane&15 (channel), row = 4*(lane>>4)+reg (pixel).
#pragma unroll
    for (int mt = 0; mt < 4; ++mt) {
#pragma unroll
        for (int ntl = 0; ntl < 2; ++ntl) {
            int ch = wv * 32 + ntl * 16 + l15;
            int bv = bias[ch];
#pragma unroll
            for (int r = 0; r < 4; ++r) {
                int pixel = mbase + mt * 16 + l4 * 4 + r;
                out[pixel * OUT_C + ch] = acc[mt][ntl][r] + bv;
            }
        }
    }
}

// ---------------------------------------------------------------------------
// Fallback (only if workspace is too small): direct conv, 1 thread/output.
__global__ __launch_bounds__(256) void conv_naive_kernel(const int* __restrict__ x,
                                                         const int* __restrict__ wgt,
                                                         const int* __restrict__ bias,
                                                         int* __restrict__ out) {
    int idx = blockIdx.x * 256 + threadIdx.x;
    if (idx >= N_OUT) return;
    int ch  = idx & 127;
    int pix = idx >> 7;
    int n  = pix / 3136;
    int r2 = pix - n * 3136;
    int h  = r2 / 56;
    int w  = r2 - h * 56;
    int acc = bias[ch];
    for (int kh = 0; kh < 3; ++kh) {
        int hx = h + kh - 1;
        if ((unsigned)hx >= 56u) continue;
        for (int kw = 0; kw < 3; ++kw) {
            int wx = w + kw - 1;
            if ((unsigned)wx >= 56u) continue;
            const int* xp = x + ((n * 56 + hx) * 56 + wx) * 64;
            const int* wp = wgt + ch * KTOT + (kh * 3 + kw) * 64;
            for (int ic = 0; ic < 64; ++ic) acc += xp[ic] * wp[ic];
        }
    }
    out[idx] = acc;
}

// ---------------------------------------------------------------------------
extern "C" void kernel_launch(void* const* d_in, const int* in_sizes, int n_in,
                              void* d_out, int out_size, void* d_ws, size_t ws_size,
                              hipStream_t stream) {
    const int* x    = (const int*)d_in[0];
    const int* wgt  = (const int*)d_in[1];
    const int* bias = (const int*)d_in[2];
    int* out = (int*)d_out;

    if (ws_size >= (size_t)N_W) {
        char* w8 = (char*)d_ws;              // N_W bytes, B-fragment order
        pack_w_kernel<<<N_W / 256, 256, 0, stream>>>(wgt, w8);
        conv_fused_kernel<<<NPIX / BLOCK_PIX, 256, 0, stream>>>(x, w8, bias, out);
    } else {
        conv_naive_kernel<<<(N_OUT + 255) / 256, 256, 0, stream>>>(x, wgt, bias, out);
    }
}

// Round 3
// 41.608 us; speedup vs baseline: 1.4527x; 1.4527x over previous
//
#include <hip/hip_runtime.h>

typedef int int4v __attribute__((ext_vector_type(4)));

// Problem constants
#define IN_C    64
#define OUT_C   128
#define NPIX    200704      // 64*56*56
#define KTOT    576         // 3*3*64
#define N_W     73728       // 128*3*3*64
#define N_OUT   25690112    // NPIX * OUT_C

// Halo tiling: 8x8 output pixels per block, 10x10 halo in LDS.
#define PIXB    80          // bytes per halo pixel slot (64 data + 16 pad)
// halo LDS = 100 * 80 = 8000 B

// ---------------------------------------------------------------------------
// Pack weights into B-fragment order for mfma_i32_16x16x64_i8:
//   dest byte t = ((kt*8 + nt)*64 + lane)*16 + byte
//   holds W[k][n] with k = kt*64 + (lane>>4)*16 + byte, n = nt*16 + (lane&15)
// Source OHWI flat index = n*576 + k  (since k = (kh*3+kw)*64+ic).
__global__ __launch_bounds__(256) void pack_w_kernel(const int* __restrict__ wgt,
                                                     char* __restrict__ w8) {
    int t = blockIdx.x * 256 + threadIdx.x;   // t < N_W == 73728 exactly
    int byte = t & 15;
    int lane = (t >> 4) & 63;
    int ntk  = t >> 10;
    int nt   = ntk & 7;
    int kt   = ntk >> 3;                      // kt < 9
    int k = kt * 64 + ((lane >> 4) << 4) + byte;
    int n = nt * 16 + (lane & 15);
    w8[t] = (char)wgt[n * KTOT + k];
}

// ---------------------------------------------------------------------------
// Halo-tile MFMA conv. Block = 8x8 pixels x 128 channels, 4 waves.
// Raw x staged ONCE as int8 halo (10x10x64 = 8KB LDS); A-fragments are
// ds_read_b128 at tap-dependent immediate offsets. B fragments streamed
// per-kt from L2-resident w8 with 1-deep prefetch.
__global__ __launch_bounds__(256, 4) void conv_halo_kernel(const int* __restrict__ x32,
                                                           const char* __restrict__ w8,
                                                           const int* __restrict__ bias,
                                                           int* __restrict__ out) {
    __shared__ char hx[100 * PIXB];

    const int tid  = threadIdx.x;
    const int lane = tid & 63;
    const int wv   = tid >> 6;
    const int l15  = lane & 15;
    const int l4   = lane >> 4;

    // block -> (n, th, tw); 7x7 tiles per image
    const int bid = blockIdx.x;
    const int n   = bid / 49;
    const int rr  = bid - n * 49;
    const int th  = rr / 7;
    const int tw  = rr - th * 7;
    const int h0  = th * 8 - 1;               // halo origin (may be -1)
    const int w0  = tw * 8 - 1;

    // ---- Stage halo: 100 px * 4 quarters = 400 units; unit = 16B int8 out.
    for (int u = tid; u < 400; u += 256) {
        int pix = u >> 2;
        int q   = u & 3;
        int hr  = pix / 10;
        int hc  = pix - hr * 10;
        int gh  = h0 + hr;
        int gw  = w0 + hc;
        int4v pk = {0, 0, 0, 0};
        if ((unsigned)gh < 56u && (unsigned)gw < 56u) {
            const int4v* src = (const int4v*)x32 + (((n * 56 + gh) * 56 + gw) << 4) + (q << 2);
            int4v a0 = src[0], a1 = src[1], a2 = src[2], a3 = src[3];
            pk.x = (a0.x & 0xff) | ((a0.y & 0xff) << 8) | ((a0.z & 0xff) << 16) | (a0.w << 24);
            pk.y = (a1.x & 0xff) | ((a1.y & 0xff) << 8) | ((a1.z & 0xff) << 16) | (a1.w << 24);
            pk.z = (a2.x & 0xff) | ((a2.y & 0xff) << 8) | ((a2.z & 0xff) << 16) | (a2.w << 24);
            pk.w = (a3.x & 0xff) | ((a3.y & 0xff) << 8) | ((a3.z & 0xff) << 16) | (a3.w << 24);
        }
        *(int4v*)(hx + pix * PIXB + (q << 4)) = pk;
    }
    __syncthreads();

    // ---- Per-lane LDS base: pixel p = l15 (mt adds 1600B), tap (0,0).
    // p -> (pr,pc) = (p>>3, p&7); halo pixel = pr*10 + pc; +l4*16 k-quarter.
    const char* aptr = hx + ((l15 >> 3) * 10 + (l15 & 7)) * PIXB + (l4 << 4);

    int4v acc[4][2];
#pragma unroll
    for (int mt = 0; mt < 4; ++mt) {
        acc[mt][0] = (int4v){0, 0, 0, 0};
        acc[mt][1] = (int4v){0, 0, 0, 0};
    }

    // B fragment stream: kt stride 8192B, ntl stride 1024B.
    const char* wp = w8 + (((wv * 2) * 64 + lane) << 4);
    int4v bc0 = *(const int4v*)(wp);
    int4v bc1 = *(const int4v*)(wp + 1024);
    int toff = 0;
#pragma unroll 1
    for (int kt = 0; kt < 9; ++kt) {
        wp += 8192;
        int4v bn0 = bc0, bn1 = bc1;
        if (kt < 8) {
            bn0 = *(const int4v*)(wp);
            bn1 = *(const int4v*)(wp + 1024);
        }
#pragma unroll
        for (int mt = 0; mt < 4; ++mt) {
            int4v a = *(const int4v*)(aptr + toff + mt * 1600);
            acc[mt][0] = __builtin_amdgcn_mfma_i32_16x16x64_i8(a, bc0, acc[mt][0], 0, 0, 0);
            acc[mt][1] = __builtin_amdgcn_mfma_i32_16x16x64_i8(a, bc1, acc[mt][1], 0, 0, 0);
        }
        bc0 = bn0;
        bc1 = bn1;
        toff += 80;                       // next kw
        if ((kt == 2) | (kt == 5)) toff += 560;  // next kh row (800 total)
    }

    // ---- Epilogue: D col = lane&15 (channel), row = 4*(lane>>4)+r (pixel).
    int* obase = out + (((n * 56 + th * 8) * 56 + tw * 8) << 7);
#pragma unroll
    for (int mt = 0; mt < 4; ++mt) {
#pragma unroll
        for (int ntl = 0; ntl < 2; ++ntl) {
            int ch = wv * 32 + ntl * 16 + l15;
            int bv = bias[ch];
#pragma unroll
            for (int r = 0; r < 4; ++r) {
                int p  = mt * 16 + l4 * 4 + r;
                int pr = p >> 3, pc = p & 7;
                obase[((pr * 56 + pc) << 7) + ch] = acc[mt][ntl][r] + bv;
            }
        }
    }
}

// ---------------------------------------------------------------------------
// Fallback (only if workspace is too small): direct conv, 1 thread/output.
__global__ __launch_bounds__(256) void conv_naive_kernel(const int* __restrict__ x,
                                                         const int* __restrict__ wgt,
                                                         const int* __restrict__ bias,
                                                         int* __restrict__ out) {
    int idx = blockIdx.x * 256 + threadIdx.x;
    if (idx >= N_OUT) return;
    int ch  = idx & 127;
    int pix = idx >> 7;
    int n  = pix / 3136;
    int r2 = pix - n * 3136;
    int h  = r2 / 56;
    int w  = r2 - h * 56;
    int acc = bias[ch];
    for (int kh = 0; kh < 3; ++kh) {
        int hx = h + kh - 1;
        if ((unsigned)hx >= 56u) continue;
        for (int kw = 0; kw < 3; ++kw) {
            int wx = w + kw - 1;
            if ((unsigned)wx >= 56u) continue;
            const int* xp = x + ((n * 56 + hx) * 56 + wx) * 64;
            const int* wp = wgt + ch * KTOT + (kh * 3 + kw) * 64;
            for (int ic = 0; ic < 64; ++ic) acc += xp[ic] * wp[ic];
        }
    }
    out[idx] = acc;
}

// ---------------------------------------------------------------------------
extern "C" void kernel_launch(void* const* d_in, const int* in_sizes, int n_in,
                              void* d_out, int out_size, void* d_ws, size_t ws_size,
                              hipStream_t stream) {
    const int* x    = (const int*)d_in[0];
    const int* wgt  = (const int*)d_in[1];
    const int* bias = (const int*)d_in[2];
    int* out = (int*)d_out;

    if (ws_size >= (size_t)N_W) {
        char* w8 = (char*)d_ws;              // N_W bytes, B-fragment order
        pack_w_kernel<<<N_W / 256, 256, 0, stream>>>(wgt, w8);
        conv_halo_kernel<<<64 * 49, 256, 0, stream>>>(x, w8, bias, out);
    } else {
        conv_naive_kernel<<<(N_OUT + 255) / 256, 256, 0, stream>>>(x, wgt, bias, out);
    }
}